// Round 10
// baseline (100.888 us; speedup 1.0000x reference)
//
#include <hip/hip_runtime.h>
#include <hip/hip_bf16.h>

// Problem geometry (fixed by reference config)
#define IN_F   4096
#define OUT_F  12288
#define OUT_PG 4096
#define M_ROWS 1024     // 2*512
#define R2     32       // GROUPS * R = 2*16
#define KS     16       // k-split factor (Tpart partials in d_ws; needs 2 MB)

// ---------------- Kernel A: Tpart[ks][m][r] = sum_{k in slice} x[m][k]*wA[r][k] ----
// Grid: (KS=16, 64) x 256 thr = 1024 blocks. Block = 4 waves x 4 rows = 16 rows,
// k-slice = 256 (single chunk, single sync). Stage wA chunk (32 KB) in LDS
// (coalesced); inner loop: 32 ds_read_b128, each feeding 4 rows x 4 FMA (halves
// LDS traffic vs 2-row version: 128 MB total). Butterfly tree-reduce (DPP) ->
// 2 coalesced 256B stores/wave. Also zero-fills its share of the disabled
// middle output block (16.8 MB total), issued first to drain under compute.
__global__ __launch_bounds__(256) void lora_a_kernel(
    const float* __restrict__ x, const float* __restrict__ wA,
    float* __restrict__ Tpart, float* __restrict__ out) {
  constexpr int SLICE = IN_F / KS;          // 256
  constexpr int ZC    = OUT_PG / KS;        // 256 zero-fill cols per block
  __shared__ float As[R2 * SLICE];          // 32 KB

  const int t = threadIdx.x;
  const int l = t & 63;
  const int w = t >> 6;                     // wave id
  const int ks = blockIdx.x;
  const int row0 = blockIdx.y * 16 + w * 4;
  const int kb = ks * SLICE;

  // Zero-fill share of middle block: rows by*16..+16, cols OUT_PG+ks*ZC..+ZC.
  {
    const int zrow0 = blockIdx.y * 16;
    const int zcol0 = OUT_PG + ks * ZC;
    const float4 z = {0.f, 0.f, 0.f, 0.f};
#pragma unroll
    for (int i = 0; i < 4; ++i) {           // 16*256/4 f4 / 256 thr = 4
      const int idx = t + i * 256;
      const int zr = idx >> 6;              // /(ZC/4)
      const int zc = (idx & 63) * 4;
      *reinterpret_cast<float4*>(&out[(zrow0 + zr) * OUT_F + zcol0 + zc]) = z;
    }
  }

  // Stage 32x256 wA chunk: flat f = r*256+kk, 8 float4 per thread, coalesced.
#pragma unroll
  for (int i = 0; i < 8; ++i) {
    const int f = t * 4 + i * 1024;
    const int r = f >> 8, kk = f & 255;
    *reinterpret_cast<float4*>(&As[f]) =
        *reinterpret_cast<const float4*>(&wA[r * IN_F + kb + kk]);
  }
  __syncthreads();

  float4 xv[4];
#pragma unroll
  for (int m = 0; m < 4; ++m)
    xv[m] = *reinterpret_cast<const float4*>(&x[(row0 + m) * IN_F + kb + l * 4]);

  float acc[4][32];
#pragma unroll
  for (int m = 0; m < 4; ++m)
#pragma unroll
    for (int r = 0; r < 32; ++r) acc[m][r] = 0.f;

#pragma unroll
  for (int r = 0; r < 32; ++r) {
    const float4 av = *reinterpret_cast<const float4*>(&As[r * SLICE + l * 4]);
#pragma unroll
    for (int m = 0; m < 4; ++m)
      acc[m][r] += xv[m].x * av.x + xv[m].y * av.y + xv[m].z * av.z + xv[m].w * av.w;
  }

  // Butterfly tree-reduce per row: after masked steps + xor-32 merge, every
  // lane holds the full sum for r = l&31.
  float v[4];
#pragma unroll
  for (int m2 = 0; m2 < 4; ++m2) {
#pragma unroll
    for (int m = 16; m >= 1; m >>= 1) {
#pragma unroll
      for (int i = 0; i < m; ++i) {
        const float a = acc[m2][i], b = acc[m2][i + m];
        const float mine   = (l & m) ? b : a;
        const float theirs = (l & m) ? a : b;
        acc[m2][i] = mine + __shfl_xor(theirs, m, 64);
      }
    }
    v[m2] = acc[m2][0] + __shfl_xor(acc[m2][0], 32, 64);
  }
  // Row pair p: lanes 0..31 -> row0+2p, lanes 32..63 -> row0+2p+1 (256B/store).
#pragma unroll
  for (int p = 0; p < 2; ++p) {
    const float outv = (l < 32) ? v[2 * p] : v[2 * p + 1];
    Tpart[(ks * M_ROWS + row0 + 2 * p + (l >> 5)) * R2 + (l & 31)] = outv;
  }
}

// ---------------- Kernel B: out[m][col] = sum_r T[m][g*16+r] * wB[col][r] ----------
// Covers ONLY the two LoRA-enabled output blocks (middle block zeroed by A).
// Grid: (32, 32) x 256 thr = 1024 blocks (4/CU). Block tile 32 rows x 256 cols.
// bx<16 -> group 0 (out cols 0..4096); bx>=16 -> group 1 (out cols 8192..12288).
// wB tile staged TRANSPOSED in LDS; T tile (KS-partial sum, 2-chain ILP) in
// LDS, broadcast reads; per-thread 8 rows x 4 cols, coalesced f4 stores.
__global__ __launch_bounds__(256) void lora_b_kernel(
    const float* __restrict__ Tpart, const float* __restrict__ wB,
    float* __restrict__ out) {
  const int t = threadIdx.x;
  const int bx = blockIdx.x;            // 0..31
  const int by = blockIdx.y;            // 0..31
  const int g = bx >> 4;                // 0,1
  const int jbase = (bx & 15) << 8;     // within-group col base
  const int colbase = g ? (2 * OUT_PG + jbase) : jbase;
  const int rbase = by << 5;            // 32 rows
  const int cq = t & 63;                // col quad
  const int rowg = t >> 6;              // wave id (uniform)

  __shared__ float BsT[16 * 260];       // [r][col], stride 260 (pad 4)
  __shared__ float Ts[32 * 16];

  // Stage wB^T: 256 cols x 16 r = 1024 f4, 4 per thread; coalesced global reads.
#pragma unroll
  for (int i = 0; i < 4; ++i) {
    const int idx = t + i * 256;
    const int c = idx >> 2, r0 = (idx & 3) * 4;
    const float4 v = *reinterpret_cast<const float4*>(
        &wB[(g * OUT_PG + jbase + c) * 16 + r0]);
    BsT[(r0 + 0) * 260 + c] = v.x;
    BsT[(r0 + 1) * 260 + c] = v.y;
    BsT[(r0 + 2) * 260 + c] = v.z;
    BsT[(r0 + 3) * 260 + c] = v.w;
  }
  // Stage T tile with KS-partial sum (2 independent chains for ILP).
  if (t < 128) {
    const int row = t >> 2, q = t & 3;
    float4 s0 = {0.f, 0.f, 0.f, 0.f}, s1 = {0.f, 0.f, 0.f, 0.f};
#pragma unroll
    for (int ks = 0; ks < KS; ks += 2) {
      const float4 v0 = *reinterpret_cast<const float4*>(
          &Tpart[((ks + 0) * M_ROWS + rbase + row) * R2 + g * 16 + q * 4]);
      const float4 v1 = *reinterpret_cast<const float4*>(
          &Tpart[((ks + 1) * M_ROWS + rbase + row) * R2 + g * 16 + q * 4]);
      s0.x += v0.x; s0.y += v0.y; s0.z += v0.z; s0.w += v0.w;
      s1.x += v1.x; s1.y += v1.y; s1.z += v1.z; s1.w += v1.w;
    }
    const float4 s = {s0.x + s1.x, s0.y + s1.y, s0.z + s1.z, s0.w + s1.w};
    *reinterpret_cast<float4*>(&Ts[row * 16 + q * 4]) = s;
  }
  __syncthreads();

  // Per-thread B: brow[r] = B values of this thread's 4 cols at rank r.
  float4 brow[16];
#pragma unroll
  for (int r = 0; r < 16; ++r)
    brow[r] = *reinterpret_cast<const float4*>(&BsT[r * 260 + cq * 4]);

#pragma unroll
  for (int rr = 0; rr < 8; ++rr) {
    const int rowl = rowg * 8 + rr;
    float ts[16];
#pragma unroll
    for (int q = 0; q < 4; ++q)
      *reinterpret_cast<float4*>(&ts[q * 4]) =
          *reinterpret_cast<const float4*>(&Ts[rowl * 16 + q * 4]);  // broadcast
    float a0 = 0.f, a1 = 0.f, a2 = 0.f, a3 = 0.f;
#pragma unroll
    for (int r = 0; r < 16; ++r) {
      a0 += ts[r] * brow[r].x;
      a1 += ts[r] * brow[r].y;
      a2 += ts[r] * brow[r].z;
      a3 += ts[r] * brow[r].w;
    }
    const float4 accv = {a0, a1, a2, a3};
    *reinterpret_cast<float4*>(&out[(rbase + rowl) * OUT_F + colbase + cq * 4]) = accv;
  }
}

extern "C" void kernel_launch(void* const* d_in, const int* in_sizes, int n_in,
                              void* d_out, int out_size, void* d_ws, size_t ws_size,
                              hipStream_t stream) {
  const float* x  = (const float*)d_in[0];   // (2,512,4096) f32
  const float* wA = (const float*)d_in[1];   // (32,4096) f32
  const float* wB = (const float*)d_in[2];   // (8192,16) f32
  float* out = (float*)d_out;                // (2,512,12288) f32
  float* Tpart = (float*)d_ws;               // (KS,1024,32) f32 = 2 MB

  lora_a_kernel<<<dim3(KS, M_ROWS / 16), 256, 0, stream>>>(x, wA, Tpart, out);
  lora_b_kernel<<<dim3(32, M_ROWS / 32), 256, 0, stream>>>(Tpart, wB, out);
}